// Round 19
// baseline (332.062 us; speedup 1.0000x reference)
//
#include <hip/hip_runtime.h>
#include <hip/hip_bf16.h>

// Joiner: out[m, v] = tanh(enc[b_m, t_m, :] + dec[b_m, u_m, :]) @ W[v, :]^T + bias[v]
// M ~ 295k rows, K = 512, V = 500 (padded to 512).
// r19 = r18 (239us) + K-halved intra-block pipeline: A staged as two [64][256] i8
// halves; GEMM(ks0-3) on half0 runs WITH half1's gather consumes interleaved
// (loads issued pre-barrier), filling MFMA gaps with VALU and load-stalls with MFMA.
// B each-used-once (no byte change); acc single [4][4]; epilogue verbatim.
// Chain: pipelined(full ws) -> i8+f32 gather (r17) -> bf16 GEMM fallback.

typedef __attribute__((ext_vector_type(4))) int   i32x4;    // i8 MFMA operands/acc
typedef __attribute__((ext_vector_type(4))) float f32x4;    // NT store
typedef __attribute__((ext_vector_type(8))) short short8;   // fallback bf16 frag

__device__ __forceinline__ unsigned short f2bf(float v) {
    unsigned int u = __float_as_uint(v);
    u += 0x7fffu + ((u >> 16) & 1u);
    return (unsigned short)(u >> 16);
}

__device__ __forceinline__ unsigned pack_bf16x2(float a, float b) {
    __hip_bfloat162 h = __float22bfloat162_rn(make_float2(a, b));
    unsigned u;
    __builtin_memcpy(&u, &h, 4);
    return u;
}

__device__ __forceinline__ float bflo(unsigned u) { return __uint_as_float(u << 16); }
__device__ __forceinline__ float bfhi(unsigned u) { return __uint_as_float(u & 0xffff0000u); }

// Symmetric fast tanh: t = e^{2x}; (t-1)/(t+1). Safe for |x| < 44.
__device__ __forceinline__ float tanh_fast(float x) {
    float t = __builtin_amdgcn_exp2f(x * 2.8853900817779268f);
    return (t - 1.0f) * __builtin_amdgcn_rcpf(t + 1.0f);
}

// rint(t*127) low byte via magic-add: RNE, two's complement in low 8 bits.
__device__ __forceinline__ unsigned q8(float t) {
    return __float_as_uint(fmaf(t, 127.0f, 12582912.0f)) & 0xffu;
}

// f32 -> bf16 cast (4 elems/thread), for enc/dec staging.
__global__ void prep_cast_kernel(const float* __restrict__ src,
                                 unsigned short* __restrict__ dst, int n4) {
    const int i = blockIdx.x * blockDim.x + threadIdx.x;
    if (i < n4) {
        const float4 v = reinterpret_cast<const float4*>(src)[i];
        uint2 p;
        p.x = pack_bf16x2(v.x, v.y);
        p.y = pack_bf16x2(v.z, v.w);
        reinterpret_cast<uint2*>(dst)[i] = p;
    }
}

// W (500x512 f32) -> per-row i8 (512x512, rows 500+ zero) + fac[n] = max/(127*127).
__global__ void prep_wq_kernel(const float* __restrict__ W,
                               signed char* __restrict__ qW, float* __restrict__ fac) {
    const int n   = blockIdx.x;      // 0..511
    const int tid = threadIdx.x;     // 512
    float w = 0.0f;
    if (n < 500) w = W[n * 512 + tid];
    float m = fabsf(w);
    #pragma unroll
    for (int off = 32; off; off >>= 1) m = fmaxf(m, __shfl_xor(m, off));
    __shared__ float wm[8];
    if ((tid & 63) == 0) wm[tid >> 6] = m;
    __syncthreads();
    const float mx = fmaxf(fmaxf(fmaxf(wm[0], wm[1]), fmaxf(wm[2], wm[3])),
                           fmaxf(fmaxf(wm[4], wm[5]), fmaxf(wm[6], wm[7])));
    const float inv = (mx > 0.0f) ? 127.0f / mx : 0.0f;
    qW[n * 512 + tid] = (signed char)(int)rintf(w * inv);
    if (tid == 0) fac[n] = mx * (1.0f / (127.0f * 127.0f));
}

// ===== r19 pipelined kernel: 64 rows x 512 cols, 512 thr / 8 waves, i8 GEMM =====
// A: two K-halves [64][256] i8, XOR-swizzled, at 0 / 16384. Obuf overlays [0,65792).
__global__ __launch_bounds__(512, 4)
void joiner_i8p_kernel(const unsigned short* __restrict__ encB,
                       const unsigned short* __restrict__ decB,
                       const float* __restrict__ bias,
                       const signed char* __restrict__ qW, const float* __restrict__ fac,
                       const int* __restrict__ b_idx, const int* __restrict__ t_idx,
                       const int* __restrict__ u_idx,
                       float* __restrict__ out, int M)
{
    __shared__ unsigned char Abuf[65792];

    const int tid  = threadIdx.x;
    const int lane = tid & 63;
    const int wv   = tid >> 6;          // 0..7
    const int m0   = blockIdx.x * 64;

    // ------- offsets: lane j (j<8) holds bf16-element offsets for row j*8 + wv -------
    int eoff_l, doff_l;
    {
        const int rc = min(m0 + ((lane & 7) << 3) + wv, M - 1);
        const int bi = b_idx[rc];
        eoff_l = ((bi << 9) + t_idx[rc]) << 9;   // (bi*512+ti)*512
        doff_l = ((bi << 6) + u_idx[rc]) << 9;   // (bi*64 +ui)*512
    }

    // gather: pass p covers row p*8 + wv; lane covers 4 bf16 at k = h*256 + lane*4.
    auto gload = [&](int p, int h, uint2& e, uint2& d) {
        const int eo   = __builtin_amdgcn_readlane(eoff_l, p) + h * 256 + lane * 4;
        const int dofs = __builtin_amdgcn_readlane(doff_l, p) + h * 256 + lane * 4;
        e = *reinterpret_cast<const uint2*>(encB + eo);
        d = *reinterpret_cast<const uint2*>(decB + dofs);
    };
    auto gconsume = [&](int p, int h, uint2 e, uint2 d) {
        const unsigned u = q8(tanh_fast(bflo(e.x) + bflo(d.x)))
                         | (q8(tanh_fast(bfhi(e.x) + bfhi(d.x))) << 8)
                         | (q8(tanh_fast(bflo(e.y) + bflo(d.y))) << 16)
                         | (q8(tanh_fast(bfhi(e.y) + bfhi(d.y))) << 24);
        const int r = p * 8 + wv;
        const int byteoff = h * 16384 + r * 256 + ((lane * 4) ^ ((r & 7) << 4));
        *reinterpret_cast<unsigned*>(&Abuf[byteoff]) = u;
    };

    // ------- wave geometry for GEMM -------
    const int l15  = lane & 15;
    const int lk   = lane >> 4;
    const int n_wave = wv << 6;
    const int a_swz  = (l15 & 7) << 4;

    const signed char* wq = qW + ((size_t)(n_wave + l15)) * 512 + lk * 16;
    auto loadB = [&](int ks, int nf) -> i32x4 {
        return *reinterpret_cast<const i32x4*>(wq + nf * (16 * 512) + ks * 64);
    };

    // ------- stage half0 (16 loads in flight, then consume) -------
    uint2 ge[8], gd[8];
    #pragma unroll
    for (int p = 0; p < 8; ++p) gload(p, 0, ge[p], gd[p]);
    #pragma unroll
    for (int p = 0; p < 8; ++p) gconsume(p, 0, ge[p], gd[p]);
    // issue half1 loads (in flight across the barrier and GEMM0)
    #pragma unroll
    for (int p = 0; p < 8; ++p) gload(p, 1, ge[p], gd[p]);

    i32x4 acc[4][4];
    #pragma unroll
    for (int mf = 0; mf < 4; ++mf)
        #pragma unroll
        for (int nf = 0; nf < 4; ++nf)
            acc[mf][nf] = (i32x4)(0);

    i32x4 Bf[2][4];
    #pragma unroll
    for (int nf = 0; nf < 4; ++nf) Bf[0][nf] = loadB(0, nf);
    #pragma unroll
    for (int nf = 0; nf < 4; ++nf) Bf[1][nf] = loadB(1, nf);

    __syncthreads();                       // A0 ready

    // ------- GEMM0 (ks 0..3 from A0) interleaved with half1 consumes -------
    #pragma unroll
    for (int ks = 0; ks < 4; ++ks) {
        gconsume(2 * ks,     1, ge[2 * ks],     gd[2 * ks]);
        gconsume(2 * ks + 1, 1, ge[2 * ks + 1], gd[2 * ks + 1]);
        i32x4 a[4];
        #pragma unroll
        for (int mf = 0; mf < 4; ++mf) {
            const int addr = (mf * 16 + l15) * 256 + ((ks * 64 + lk * 16) ^ a_swz);
            a[mf] = *reinterpret_cast<const i32x4*>(&Abuf[addr]);
        }
        __builtin_amdgcn_s_setprio(1);
        #pragma unroll
        for (int mf = 0; mf < 4; ++mf)
            #pragma unroll
            for (int nf = 0; nf < 4; ++nf)
                acc[mf][nf] = __builtin_amdgcn_mfma_i32_16x16x64_i8(a[mf], Bf[ks & 1][nf], acc[mf][nf], 0, 0, 0);
        __builtin_amdgcn_s_setprio(0);
        #pragma unroll
        for (int nf = 0; nf < 4; ++nf) Bf[ks & 1][nf] = loadB(ks + 2, nf);
    }

    __syncthreads();                       // A1 writes complete

    // ------- GEMM1 (ks 4..7 from A1) -------
    #pragma unroll
    for (int ks = 4; ks < 8; ++ks) {
        i32x4 a[4];
        #pragma unroll
        for (int mf = 0; mf < 4; ++mf) {
            const int addr = 16384 + (mf * 16 + l15) * 256 + (((ks - 4) * 64 + lk * 16) ^ a_swz);
            a[mf] = *reinterpret_cast<const i32x4*>(&Abuf[addr]);
        }
        __builtin_amdgcn_s_setprio(1);
        #pragma unroll
        for (int mf = 0; mf < 4; ++mf)
            #pragma unroll
            for (int nf = 0; nf < 4; ++nf)
                acc[mf][nf] = __builtin_amdgcn_mfma_i32_16x16x64_i8(a[mf], Bf[ks & 1][nf], acc[mf][nf], 0, 0, 0);
        __builtin_amdgcn_s_setprio(0);
        if (ks < 6) {
            #pragma unroll
            for (int nf = 0; nf < 4; ++nf) Bf[ks & 1][nf] = loadB(ks + 2, nf);
        }
    }

    // ------- Epilogue: dequant + bias, Obuf transpose, NT stores (r18 verbatim) -------
    float accf[4][4][4];
    #pragma unroll
    for (int nf = 0; nf < 4; ++nf) {
        const int col = n_wave + nf * 16 + l15;
        const float fc = (col < 500) ? fac[col] : 0.0f;
        const float bv = (col < 500) ? bias[col] : 0.0f;
        #pragma unroll
        for (int mf = 0; mf < 4; ++mf)
            #pragma unroll
            for (int j = 0; j < 4; ++j)
                accf[mf][nf][j] = (float)acc[mf][nf][j] * fc + bv;
    }

    float* Obuf = reinterpret_cast<float*>(Abuf);   // [64][257] f32 overlay
    #pragma unroll
    for (int h = 0; h < 2; ++h) {
        __syncthreads();                  // covers A reads before Obuf overwrite
        if ((wv >> 2) == h) {
            const int lcol = (wv & 3) << 6;
            #pragma unroll
            for (int mf = 0; mf < 4; ++mf)
                #pragma unroll
                for (int nf = 0; nf < 4; ++nf)
                    #pragma unroll
                    for (int j = 0; j < 4; ++j) {
                        const int r = mf * 16 + lk * 4 + j;
                        Obuf[r * 257 + lcol + nf * 16 + l15] = accf[mf][nf][j];
                    }
        }
        __syncthreads();
        #pragma unroll
        for (int i = 0; i < 8; ++i) {
            const int linear = i * 512 + tid;
            const int r  = linear >> 6;
            const int c4 = linear & 63;
            const int row = m0 + r;
            const int col = (h << 8) + (c4 << 2);
            if (row < M && col < 500) {
                const f32x4 v = *reinterpret_cast<const f32x4*>(&Obuf[r * 257 + (c4 << 2)]);
                __builtin_nontemporal_store(v, reinterpret_cast<f32x4*>(&out[(size_t)row * 500 + col]));
            }
        }
    }
}

// ===== mid fallback: r17 i8 kernel with f32 gather (no ws for bf16 inputs) =====
__global__ __launch_bounds__(512, 4)
void joiner_i8_kernel(const float* __restrict__ enc, const float* __restrict__ dec,
                      const float* __restrict__ bias,
                      const signed char* __restrict__ qW, const float* __restrict__ fac,
                      const int* __restrict__ b_idx, const int* __restrict__ t_idx,
                      const int* __restrict__ u_idx,
                      float* __restrict__ out, int M)
{
    __shared__ unsigned char Abuf[65792];
    const int tid  = threadIdx.x;
    const int lane = tid & 63;
    const int m0   = blockIdx.x * 64;

    const int rr = tid >> 7;
    int eoff_l, doff_l;
    {
        const int rc = min(m0 + ((lane & 15) << 2) + rr, M - 1);
        const int bi = b_idx[rc];
        eoff_l = ((bi << 9) + t_idx[rc]) << 9;
        doff_l = ((bi << 6) + u_idx[rc]) << 9;
    }
    {
        const int kq  = tid & 127;
        const int kq4 = kq << 2;
        float4 es[6], dsv[6];
        #pragma unroll
        for (int i = 0; i < 6; ++i) {
            es[i]  = *reinterpret_cast<const float4*>(enc + __builtin_amdgcn_readlane(eoff_l, i) + kq4);
            dsv[i] = *reinterpret_cast<const float4*>(dec + __builtin_amdgcn_readlane(doff_l, i) + kq4);
        }
        #pragma unroll
        for (int p = 0; p < 16; ++p) {
            const int s = p % 6;
            const float4 e = es[s];
            const float4 d = dsv[s];
            if (p + 6 < 16) {
                es[s]  = *reinterpret_cast<const float4*>(enc + __builtin_amdgcn_readlane(eoff_l, p + 6) + kq4);
                dsv[s] = *reinterpret_cast<const float4*>(dec + __builtin_amdgcn_readlane(doff_l, p + 6) + kq4);
            }
            const unsigned u = q8(tanh_fast(e.x + d.x))
                             | (q8(tanh_fast(e.y + d.y)) << 8)
                             | (q8(tanh_fast(e.z + d.z)) << 16)
                             | (q8(tanh_fast(e.w + d.w)) << 24);
            const int r = p * 4 + rr;
            const int byteoff = (r * 512) + ((kq * 4) ^ ((r & 7) << 4));
            *reinterpret_cast<unsigned*>(&Abuf[byteoff]) = u;
        }
    }
    const int wv   = tid >> 6;
    const int l15  = lane & 15;
    const int lk   = lane >> 4;
    const int n_wave = wv << 6;
    const int a_swz  = (l15 & 7) << 4;

    i32x4 acc[4][4];
    #pragma unroll
    for (int mf = 0; mf < 4; ++mf)
        #pragma unroll
        for (int nf = 0; nf < 4; ++nf)
            acc[mf][nf] = (i32x4)(0);

    const signed char* wq = qW + ((size_t)(n_wave + l15)) * 512 + lk * 16;
    auto loadB = [&](int ks, int nf) -> i32x4 {
        return *reinterpret_cast<const i32x4*>(wq + nf * (16 * 512) + ks * 64);
    };

    i32x4 Bf[2][4];
    #pragma unroll
    for (int nf = 0; nf < 4; ++nf) Bf[0][nf] = loadB(0, nf);
    #pragma unroll
    for (int nf = 0; nf < 4; ++nf) Bf[1][nf] = loadB(1, nf);

    __syncthreads();

    #pragma unroll
    for (int ks = 0; ks < 8; ++ks) {
        i32x4 a[4];
        #pragma unroll
        for (int mf = 0; mf < 4; ++mf) {
            const int addr = ((mf * 16 + l15) << 9) + ((ks * 64 + lk * 16) ^ a_swz);
            a[mf] = *reinterpret_cast<const i32x4*>(&Abuf[addr]);
        }
        __builtin_amdgcn_s_setprio(1);
        #pragma unroll
        for (int mf = 0; mf < 4; ++mf)
            #pragma unroll
            for (int nf = 0; nf < 4; ++nf)
                acc[mf][nf] = __builtin_amdgcn_mfma_i32_16x16x64_i8(a[mf], Bf[ks & 1][nf], acc[mf][nf], 0, 0, 0);
        __builtin_amdgcn_s_setprio(0);
        if (ks < 6) {
            #pragma unroll
            for (int nf = 0; nf < 4; ++nf) Bf[ks & 1][nf] = loadB(ks + 2, nf);
        }
    }

    float accf[4][4][4];
    #pragma unroll
    for (int nf = 0; nf < 4; ++nf) {
        const int col = n_wave + nf * 16 + l15;
        const float fc = (col < 500) ? fac[col] : 0.0f;
        const float bv = (col < 500) ? bias[col] : 0.0f;
        #pragma unroll
        for (int mf = 0; mf < 4; ++mf)
            #pragma unroll
            for (int j = 0; j < 4; ++j)
                accf[mf][nf][j] = (float)acc[mf][nf][j] * fc + bv;
    }

    float* Obuf = reinterpret_cast<float*>(Abuf);
    #pragma unroll
    for (int h = 0; h < 2; ++h) {
        __syncthreads();
        if ((wv >> 2) == h) {
            const int lcol = (wv & 3) << 6;
            #pragma unroll
            for (int mf = 0; mf < 4; ++mf)
                #pragma unroll
                for (int nf = 0; nf < 4; ++nf)
                    #pragma unroll
                    for (int j = 0; j < 4; ++j) {
                        const int r = mf * 16 + lk * 4 + j;
                        Obuf[r * 257 + lcol + nf * 16 + l15] = accf[mf][nf][j];
                    }
        }
        __syncthreads();
        #pragma unroll
        for (int i = 0; i < 8; ++i) {
            const int linear = i * 512 + tid;
            const int r  = linear >> 6;
            const int c4 = linear & 63;
            const int row = m0 + r;
            const int col = (h << 8) + (c4 << 2);
            if (row < M && col < 500) {
                const f32x4 v = *reinterpret_cast<const f32x4*>(&Obuf[r * 257 + (c4 << 2)]);
                __builtin_nontemporal_store(v, reinterpret_cast<f32x4*>(&out[(size_t)row * 500 + col]));
            }
        }
    }
}

// ===== last-resort fallback: bf16 GEMM, f32 W in-kernel (no workspace) =====
__global__ __launch_bounds__(512, 4)
void joiner_fallback_kernel(const float* __restrict__ enc, const float* __restrict__ dec,
                            const float* __restrict__ W, const float* __restrict__ bias,
                            const int* __restrict__ b_idx, const int* __restrict__ t_idx,
                            const int* __restrict__ u_idx,
                            float* __restrict__ out, int M)
{
    __shared__ unsigned char Abuf[65792];
    const int tid  = threadIdx.x;
    const int lane = tid & 63;
    const int m0   = blockIdx.x * 64;

    const int rr = tid >> 7;
    int eoff_l, doff_l;
    {
        const int rc = min(m0 + ((lane & 15) << 2) + rr, M - 1);
        const int bi = b_idx[rc];
        eoff_l = ((bi << 9) + t_idx[rc]) << 9;
        doff_l = ((bi << 6) + u_idx[rc]) << 9;
    }
    {
        const int kq  = tid & 127;
        const int kq4 = kq << 2;
        float4 es[6], dsv[6];
        #pragma unroll
        for (int i = 0; i < 6; ++i) {
            es[i]  = *reinterpret_cast<const float4*>(enc + __builtin_amdgcn_readlane(eoff_l, i) + kq4);
            dsv[i] = *reinterpret_cast<const float4*>(dec + __builtin_amdgcn_readlane(doff_l, i) + kq4);
        }
        #pragma unroll
        for (int p = 0; p < 16; ++p) {
            const int s = p % 6;
            const float4 e = es[s];
            const float4 d = dsv[s];
            if (p + 6 < 16) {
                es[s]  = *reinterpret_cast<const float4*>(enc + __builtin_amdgcn_readlane(eoff_l, p + 6) + kq4);
                dsv[s] = *reinterpret_cast<const float4*>(dec + __builtin_amdgcn_readlane(doff_l, p + 6) + kq4);
            }
            uint2 packed;
            packed.x = pack_bf16x2(tanh_fast(e.x + d.x), tanh_fast(e.y + d.y));
            packed.y = pack_bf16x2(tanh_fast(e.z + d.z), tanh_fast(e.w + d.w));
            const int r = p * 4 + rr;
            const int byteoff = (r * 1024 + kq * 8) ^ ((r & 7) << 4);
            *reinterpret_cast<uint2*>(&Abuf[byteoff]) = packed;
        }
    }
    const int wv   = tid >> 6;
    const int l15  = lane & 15;
    const int lk   = lane >> 4;
    const int n_wave = wv << 6;
    const int a_swz  = (l15 & 7) << 4;

    f32x4 acc[4][4];
    #pragma unroll
    for (int mf = 0; mf < 4; ++mf)
        #pragma unroll
        for (int nf = 0; nf < 4; ++nf)
            acc[mf][nf] = (f32x4)(0.0f);

    const float* wpf = W + (((size_t)(n_wave + l15)) << 9) + (lk << 3);
    const int colbase = n_wave + l15;
    auto loadB = [&](int ks, int nf) -> short8 {
        short8 b;
        float4 w0 = make_float4(0,0,0,0), w1 = make_float4(0,0,0,0);
        if (colbase + nf * 16 < 500) {
            const float4* q = reinterpret_cast<const float4*>(wpf + nf * 8192 + ks * 32);
            w0 = q[0]; w1 = q[1];
        }
        b[0] = (short)f2bf(w0.x); b[1] = (short)f2bf(w0.y);
        b[2] = (short)f2bf(w0.z); b[3] = (short)f2bf(w0.w);
        b[4] = (short)f2bf(w1.x); b[5] = (short)f2bf(w1.y);
        b[6] = (short)f2bf(w1.z); b[7] = (short)f2bf(w1.w);
        return b;
    };

    short8 Bf[2][4];
    #pragma unroll
    for (int nf = 0; nf < 4; ++nf) Bf[0][nf] = loadB(0, nf);
    #pragma unroll
    for (int nf = 0; nf < 4; ++nf) Bf[1][nf] = loadB(1, nf);
    __syncthreads();
    #pragma unroll
    for (int ks = 0; ks < 16; ++ks) {
        short8 a[4];
        #pragma unroll
        for (int mf = 0; mf < 4; ++mf) {
            const int addr = (((mf * 16 + l15) << 10) + ks * 64 + lk * 16) ^ a_swz;
            a[mf] = *reinterpret_cast<const short8*>(&Abuf[addr]);
        }
        #pragma unroll
        for (int mf = 0; mf < 4; ++mf)
            #pragma unroll
            for (int nf = 0; nf < 4; ++nf)
                acc[mf][nf] = __builtin_amdgcn_mfma_f32_16x16x32_bf16(a[mf], Bf[ks & 1][nf], acc[mf][nf], 0, 0, 0);
        if (ks < 14) {
            #pragma unroll
            for (int nf = 0; nf < 4; ++nf) Bf[ks & 1][nf] = loadB(ks + 2, nf);
        }
    }
    #pragma unroll
    for (int nf = 0; nf < 4; ++nf) {
        const int col = n_wave + nf * 16 + l15;
        const float bv = (col < 500) ? bias[col] : 0.0f;
        #pragma unroll
        for (int mf = 0; mf < 4; ++mf)
            #pragma unroll
            for (int j = 0; j < 4; ++j)
                acc[mf][nf][j] += bv;
    }
    float* Obuf = reinterpret_cast<float*>(Abuf);
    #pragma unroll
    for (int h = 0; h < 2; ++h) {
        __syncthreads();
        if ((wv >> 2) == h) {
            const int lcol = (wv & 3) << 6;
            #pragma unroll
            for (int mf = 0; mf < 4; ++mf)
                #pragma unroll
                for (int nf = 0; nf < 4; ++nf)
                    #pragma unroll
                    for (int j = 0; j < 4; ++j) {
                        const int r = mf * 16 + lk * 4 + j;
                        Obuf[r * 257 + lcol + nf * 16 + l15] = acc[mf][nf][j];
                    }
        }
        __syncthreads();
        #pragma unroll
        for (int i = 0; i < 8; ++i) {
            const int linear = i * 512 + tid;
            const int r  = linear >> 6;
            const int c4 = linear & 63;
            const int row = m0 + r;
            const int col = (h << 8) + (c4 << 2);
            if (row < M && col < 500) {
                const f32x4 v = *reinterpret_cast<const f32x4*>(&Obuf[r * 257 + (c4 << 2)]);
                __builtin_nontemporal_store(v, reinterpret_cast<f32x4*>(&out[(size_t)row * 500 + col]));
            }
        }
    }
}

extern "C" void kernel_launch(void* const* d_in, const int* in_sizes, int n_in,
                              void* d_out, int out_size, void* d_ws, size_t ws_size,
                              hipStream_t stream) {
    const float* enc  = (const float*)d_in[0];
    const float* dec  = (const float*)d_in[1];
    const float* W    = (const float*)d_in[2];
    const float* bias = (const float*)d_in[3];
    const int* bi = (const int*)d_in[4];
    const int* ti = (const int*)d_in[5];
    const int* ui = (const int*)d_in[6];
    float* out = (float*)d_out;

    const int M = in_sizes[4];
    const int grid = (M + 63) / 64;

    const int enc_n  = in_sizes[0];                    // N*T*D f32 elements
    const int dec_n  = in_sizes[1];                    // N*U*D
    const size_t qw_bytes = (size_t)512 * 512;         // 256 KB i8
    const size_t fac_off  = qw_bytes;                  // f32[512]
    const size_t enc_off  = fac_off + 2048;
    const size_t dec_off  = enc_off + (size_t)enc_n * 2;
    const size_t need_i8  = fac_off + 2048;
    const size_t need_all = dec_off + (size_t)dec_n * 2;

    if (ws_size >= need_all) {
        signed char* qW = (signed char*)d_ws;
        float* fac = (float*)((char*)d_ws + fac_off);
        unsigned short* encB = (unsigned short*)((char*)d_ws + enc_off);
        unsigned short* decB = (unsigned short*)((char*)d_ws + dec_off);
        prep_wq_kernel<<<512, 512, 0, stream>>>(W, qW, fac);
        prep_cast_kernel<<<(enc_n / 4 + 255) / 256, 256, 0, stream>>>(enc, encB, enc_n / 4);
        prep_cast_kernel<<<(dec_n / 4 + 255) / 256, 256, 0, stream>>>(dec, decB, dec_n / 4);
        joiner_i8p_kernel<<<grid, 512, 0, stream>>>(
            encB, decB, bias, qW, fac, bi, ti, ui, out, M);
    } else if (ws_size >= need_i8) {
        signed char* qW = (signed char*)d_ws;
        float* fac = (float*)((char*)d_ws + fac_off);
        prep_wq_kernel<<<512, 512, 0, stream>>>(W, qW, fac);
        joiner_i8_kernel<<<grid, 512, 0, stream>>>(
            enc, dec, bias, qW, fac, bi, ti, ui, out, M);
    } else {
        joiner_fallback_kernel<<<grid, 512, 0, stream>>>(
            enc, dec, W, bias, bi, ti, ui, out, M);
    }
}

// Round 20
// 239.232 us; speedup vs baseline: 1.3880x; 1.3880x over previous
//
#include <hip/hip_runtime.h>
#include <hip/hip_bf16.h>

// Joiner: out[m, v] = tanh(enc[b_m, t_m, :] + dec[b_m, u_m, :]) @ W[v, :]^T + bias[v]
// M ~ 295k rows, K = 512, V = 500 (padded to 512).
// r20 = r18 verbatim (measured best: 239us). Final configuration:
//   - W per-row i8 quant in d_ws (256KB) + fac[n]; mfma_i32_16x16x64_i8, 8 K-steps
//   - enc/dec pre-cast to bf16 in d_ws (halves gather request bytes)
//   - activations q8(tanh) via exp2+rcp + magic-add RNE; i32 exact accumulation
//   - 512 thr / 8 waves / 64x64 wave tiles / 4 waves/SIMD; XOR-swizzled A (32KB)
//   - depth-6 gather ring, depth-2 B ping-pong, Obuf epilogue + NT stores
// Optimization arc: 661->450->410->363->356->246->239us (2.8x). Exhausted levers
// (each measured): concurrency (r5), barriers (r12), depth (r13), byte-reduction
// (r14/r15/r18), phase overlap (r10/r19). ~10 TB/s L2-request equilibrium,
// write stream at 1.04x ideal.

typedef __attribute__((ext_vector_type(4))) int   i32x4;    // i8 MFMA operands/acc
typedef __attribute__((ext_vector_type(4))) float f32x4;    // NT store
typedef __attribute__((ext_vector_type(8))) short short8;   // fallback bf16 frag

__device__ __forceinline__ unsigned short f2bf(float v) {
    unsigned int u = __float_as_uint(v);
    u += 0x7fffu + ((u >> 16) & 1u);
    return (unsigned short)(u >> 16);
}

__device__ __forceinline__ unsigned pack_bf16x2(float a, float b) {
    __hip_bfloat162 h = __float22bfloat162_rn(make_float2(a, b));
    unsigned u;
    __builtin_memcpy(&u, &h, 4);
    return u;
}

__device__ __forceinline__ float bflo(unsigned u) { return __uint_as_float(u << 16); }
__device__ __forceinline__ float bfhi(unsigned u) { return __uint_as_float(u & 0xffff0000u); }

// Symmetric fast tanh: t = e^{2x}; (t-1)/(t+1). Safe for |x| < 44.
__device__ __forceinline__ float tanh_fast(float x) {
    float t = __builtin_amdgcn_exp2f(x * 2.8853900817779268f);
    return (t - 1.0f) * __builtin_amdgcn_rcpf(t + 1.0f);
}

// rint(t*127) low byte via magic-add: RNE, two's complement in low 8 bits.
__device__ __forceinline__ unsigned q8(float t) {
    return __float_as_uint(fmaf(t, 127.0f, 12582912.0f)) & 0xffu;
}

// f32 -> bf16 cast (4 elems/thread), for enc/dec staging.
__global__ void prep_cast_kernel(const float* __restrict__ src,
                                 unsigned short* __restrict__ dst, int n4) {
    const int i = blockIdx.x * blockDim.x + threadIdx.x;
    if (i < n4) {
        const float4 v = reinterpret_cast<const float4*>(src)[i];
        uint2 p;
        p.x = pack_bf16x2(v.x, v.y);
        p.y = pack_bf16x2(v.z, v.w);
        reinterpret_cast<uint2*>(dst)[i] = p;
    }
}

// W (500x512 f32) -> per-row i8 (512x512, rows 500+ zero) + fac[n] = max/(127*127).
__global__ void prep_wq_kernel(const float* __restrict__ W,
                               signed char* __restrict__ qW, float* __restrict__ fac) {
    const int n   = blockIdx.x;      // 0..511
    const int tid = threadIdx.x;     // 512
    float w = 0.0f;
    if (n < 500) w = W[n * 512 + tid];
    float m = fabsf(w);
    #pragma unroll
    for (int off = 32; off; off >>= 1) m = fmaxf(m, __shfl_xor(m, off));
    __shared__ float wm[8];
    if ((tid & 63) == 0) wm[tid >> 6] = m;
    __syncthreads();
    const float mx = fmaxf(fmaxf(fmaxf(wm[0], wm[1]), fmaxf(wm[2], wm[3])),
                           fmaxf(fmaxf(wm[4], wm[5]), fmaxf(wm[6], wm[7])));
    const float inv = (mx > 0.0f) ? 127.0f / mx : 0.0f;
    qW[n * 512 + tid] = (signed char)(int)rintf(w * inv);
    if (tid == 0) fac[n] = mx * (1.0f / (127.0f * 127.0f));
}

// Block: 64 rows x 512 cols. 512 threads = 8 waves, wave tile 64x64.
// BF16G: gather from bf16-cast enc/dec in ws (8B/lane) vs f32 originals (16B/lane).
template<bool BF16G>
__global__ __launch_bounds__(512, 4)
void joiner_i8_kernel(const float* __restrict__ enc, const float* __restrict__ dec,
                      const unsigned short* __restrict__ encB,
                      const unsigned short* __restrict__ decB,
                      const float* __restrict__ bias,
                      const signed char* __restrict__ qW, const float* __restrict__ fac,
                      const int* __restrict__ b_idx, const int* __restrict__ t_idx,
                      const int* __restrict__ u_idx,
                      float* __restrict__ out, int M)
{
    // Union: phase1/2 = [64][512] i8 (32KB, XOR-swizzled); epilogue = [64][257] f32.
    __shared__ unsigned char Abuf[65792];

    const int tid  = threadIdx.x;
    const int lane = tid & 63;
    const int m0   = blockIdx.x * 64;   // natural order: blocks share enc/dec + qW in L2

    // ------- Phase 0 (barrier-free): row offsets into lane registers -------
    const int rr = tid >> 7;            // 0..3
    int eoff_l, doff_l;
    {
        const int rc = min(m0 + ((lane & 15) << 2) + rr, M - 1);
        const int bi = b_idx[rc];
        eoff_l = ((bi << 9) + t_idx[rc]) << 9;   // (bi*512+ti)*512 element offset
        doff_l = ((bi << 6) + u_idx[rc]) << 9;   // (bi*64 +ui)*512 element offset
    }

    // ------- Phase 1: activations -> LDS (i8), 4 rows/pass, depth-6 ring -------
    {
        const int kq  = tid & 127;      // 4-element chunk in 512-wide row
        const int kq4 = kq << 2;

        if constexpr (BF16G) {
            uint2 es[6], dsv[6];
            #pragma unroll
            for (int i = 0; i < 6; ++i) {
                const int eo = __builtin_amdgcn_readlane(eoff_l, i);
                const int dofs = __builtin_amdgcn_readlane(doff_l, i);
                es[i]  = *reinterpret_cast<const uint2*>(encB + eo + kq4);
                dsv[i] = *reinterpret_cast<const uint2*>(decB + dofs + kq4);
            }
            #pragma unroll
            for (int p = 0; p < 16; ++p) {
                const int s = p % 6;    // compile-time under full unroll
                const uint2 e = es[s];
                const uint2 d = dsv[s];
                if (p + 6 < 16) {
                    const int eo = __builtin_amdgcn_readlane(eoff_l, p + 6);
                    const int dofs = __builtin_amdgcn_readlane(doff_l, p + 6);
                    es[s]  = *reinterpret_cast<const uint2*>(encB + eo + kq4);
                    dsv[s] = *reinterpret_cast<const uint2*>(decB + dofs + kq4);
                }
                const unsigned u = q8(tanh_fast(bflo(e.x) + bflo(d.x)))
                                 | (q8(tanh_fast(bfhi(e.x) + bfhi(d.x))) << 8)
                                 | (q8(tanh_fast(bflo(e.y) + bflo(d.y))) << 16)
                                 | (q8(tanh_fast(bfhi(e.y) + bfhi(d.y))) << 24);
                const int r = p * 4 + rr;
                const int byteoff = (r * 512) + ((kq * 4) ^ ((r & 7) << 4));
                *reinterpret_cast<unsigned*>(&Abuf[byteoff]) = u;
            }
        } else {
            float4 es[6], dsv[6];
            #pragma unroll
            for (int i = 0; i < 6; ++i) {
                const int eo = __builtin_amdgcn_readlane(eoff_l, i);
                const int dofs = __builtin_amdgcn_readlane(doff_l, i);
                es[i]  = *reinterpret_cast<const float4*>(enc + eo + kq4);
                dsv[i] = *reinterpret_cast<const float4*>(dec + dofs + kq4);
            }
            #pragma unroll
            for (int p = 0; p < 16; ++p) {
                const int s = p % 6;
                const float4 e = es[s];
                const float4 d = dsv[s];
                if (p + 6 < 16) {
                    const int eo = __builtin_amdgcn_readlane(eoff_l, p + 6);
                    const int dofs = __builtin_amdgcn_readlane(doff_l, p + 6);
                    es[s]  = *reinterpret_cast<const float4*>(enc + eo + kq4);
                    dsv[s] = *reinterpret_cast<const float4*>(dec + dofs + kq4);
                }
                const unsigned u = q8(tanh_fast(e.x + d.x))
                                 | (q8(tanh_fast(e.y + d.y)) << 8)
                                 | (q8(tanh_fast(e.z + d.z)) << 16)
                                 | (q8(tanh_fast(e.w + d.w)) << 24);
                const int r = p * 4 + rr;
                const int byteoff = (r * 512) + ((kq * 4) ^ ((r & 7) << 4));
                *reinterpret_cast<unsigned*>(&Abuf[byteoff]) = u;
            }
        }
    }

    // ------- Phase 2: i8 MFMA GEMM, wave tile 64x64, 8 K-steps, depth-2 B prefetch -------
    const int wv   = tid >> 6;          // wave 0..7 -> cols [wv*64, wv*64+64)
    const int l15  = lane & 15;
    const int lk   = lane >> 4;
    const int n_wave = wv << 6;
    const int a_swz  = (l15 & 7) << 4;

    i32x4 acc[4][4];
    #pragma unroll
    for (int mf = 0; mf < 4; ++mf)
        #pragma unroll
        for (int nf = 0; nf < 4; ++nf)
            acc[mf][nf] = (i32x4)(0);

    const signed char* wq = qW + ((size_t)(n_wave + l15)) * 512 + lk * 16;
    auto loadB = [&](int ks, int nf) -> i32x4 {
        return *reinterpret_cast<const i32x4*>(wq + nf * (16 * 512) + ks * 64);
    };

    i32x4 Bf[2][4];
    #pragma unroll
    for (int nf = 0; nf < 4; ++nf) Bf[0][nf] = loadB(0, nf);
    #pragma unroll
    for (int nf = 0; nf < 4; ++nf) Bf[1][nf] = loadB(1, nf);

    __syncthreads();                       // Abuf ready

    #pragma unroll
    for (int ks = 0; ks < 8; ++ks) {       // full unroll: ks&1 compile-time
        i32x4 a[4];
        #pragma unroll
        for (int mf = 0; mf < 4; ++mf) {
            const int addr = ((mf * 16 + l15) << 9) + ((ks * 64 + lk * 16) ^ a_swz);
            a[mf] = *reinterpret_cast<const i32x4*>(&Abuf[addr]);
        }
        __builtin_amdgcn_s_setprio(1);
        #pragma unroll
        for (int mf = 0; mf < 4; ++mf)
            #pragma unroll
            for (int nf = 0; nf < 4; ++nf)
                acc[mf][nf] = __builtin_amdgcn_mfma_i32_16x16x64_i8(a[mf], Bf[ks & 1][nf], acc[mf][nf], 0, 0, 0);
        __builtin_amdgcn_s_setprio(0);
        if (ks < 6) {
            #pragma unroll
            for (int nf = 0; nf < 4; ++nf) Bf[ks & 1][nf] = loadB(ks + 2, nf);
        }
    }

    // ------- Epilogue: dequant + bias, then Obuf + NT stores -------
    float accf[4][4][4];
    #pragma unroll
    for (int nf = 0; nf < 4; ++nf) {
        const int col = n_wave + nf * 16 + l15;
        const float fc = (col < 500) ? fac[col] : 0.0f;
        const float bv = (col < 500) ? bias[col] : 0.0f;
        #pragma unroll
        for (int mf = 0; mf < 4; ++mf)
            #pragma unroll
            for (int j = 0; j < 4; ++j)
                accf[mf][nf][j] = (float)acc[mf][nf][j] * fc + bv;
    }

    float* Obuf = reinterpret_cast<float*>(Abuf);   // [64][257] f32
    #pragma unroll
    for (int h = 0; h < 2; ++h) {
        __syncthreads();                  // protects Abuf/Obuf reuse
        if ((wv >> 2) == h) {
            const int lcol = (wv & 3) << 6;
            #pragma unroll
            for (int mf = 0; mf < 4; ++mf)
                #pragma unroll
                for (int nf = 0; nf < 4; ++nf)
                    #pragma unroll
                    for (int j = 0; j < 4; ++j) {
                        const int r = mf * 16 + lk * 4 + j;
                        Obuf[r * 257 + lcol + nf * 16 + l15] = accf[mf][nf][j];
                    }
        }
        __syncthreads();
        // 64 rows x 64 float4-chunks per half; 1KB contiguous per wave per iter.
        #pragma unroll
        for (int i = 0; i < 8; ++i) {
            const int linear = i * 512 + tid;
            const int r  = linear >> 6;
            const int c4 = linear & 63;
            const int row = m0 + r;
            const int col = (h << 8) + (c4 << 2);
            if (row < M && col < 500) {
                const f32x4 v = *reinterpret_cast<const f32x4*>(&Obuf[r * 257 + (c4 << 2)]);
                __builtin_nontemporal_store(v, reinterpret_cast<f32x4*>(&out[(size_t)row * 500 + col]));
            }
        }
    }
}

// ---- last-resort fallback (r13 structure, bf16 GEMM, f32 W in-kernel) ----
__global__ __launch_bounds__(512, 4)
void joiner_fallback_kernel(const float* __restrict__ enc, const float* __restrict__ dec,
                            const float* __restrict__ W, const float* __restrict__ bias,
                            const int* __restrict__ b_idx, const int* __restrict__ t_idx,
                            const int* __restrict__ u_idx,
                            float* __restrict__ out, int M)
{
    __shared__ unsigned char Abuf[65792];
    const int tid  = threadIdx.x;
    const int lane = tid & 63;
    const int m0   = blockIdx.x * 64;

    const int rr = tid >> 7;
    int eoff_l, doff_l;
    {
        const int rc = min(m0 + ((lane & 15) << 2) + rr, M - 1);
        const int bi = b_idx[rc];
        eoff_l = ((bi << 9) + t_idx[rc]) << 9;
        doff_l = ((bi << 6) + u_idx[rc]) << 9;
    }
    {
        const int kq  = tid & 127;
        const int kq4 = kq << 2;
        float4 es[6], dsv[6];
        #pragma unroll
        for (int i = 0; i < 6; ++i) {
            es[i]  = *reinterpret_cast<const float4*>(enc + __builtin_amdgcn_readlane(eoff_l, i) + kq4);
            dsv[i] = *reinterpret_cast<const float4*>(dec + __builtin_amdgcn_readlane(doff_l, i) + kq4);
        }
        #pragma unroll
        for (int p = 0; p < 16; ++p) {
            const int s = p % 6;
            const float4 e = es[s];
            const float4 d = dsv[s];
            if (p + 6 < 16) {
                es[s]  = *reinterpret_cast<const float4*>(enc + __builtin_amdgcn_readlane(eoff_l, p + 6) + kq4);
                dsv[s] = *reinterpret_cast<const float4*>(dec + __builtin_amdgcn_readlane(doff_l, p + 6) + kq4);
            }
            uint2 packed;
            packed.x = pack_bf16x2(tanh_fast(e.x + d.x), tanh_fast(e.y + d.y));
            packed.y = pack_bf16x2(tanh_fast(e.z + d.z), tanh_fast(e.w + d.w));
            const int r = p * 4 + rr;
            const int byteoff = (r * 1024 + kq * 8) ^ ((r & 7) << 4);
            *reinterpret_cast<uint2*>(&Abuf[byteoff]) = packed;
        }
    }
    const int wv   = tid >> 6;
    const int l15  = lane & 15;
    const int lk   = lane >> 4;
    const int n_wave = wv << 6;
    const int a_swz  = (l15 & 7) << 4;

    f32x4 acc[4][4];
    #pragma unroll
    for (int mf = 0; mf < 4; ++mf)
        #pragma unroll
        for (int nf = 0; nf < 4; ++nf)
            acc[mf][nf] = (f32x4)(0.0f);

    const float* wpf = W + (((size_t)(n_wave + l15)) << 9) + (lk << 3);
    const int colbase = n_wave + l15;
    auto loadB = [&](int ks, int nf) -> short8 {
        short8 b;
        float4 w0 = make_float4(0,0,0,0), w1 = make_float4(0,0,0,0);
        if (colbase + nf * 16 < 500) {
            const float4* q = reinterpret_cast<const float4*>(wpf + nf * 8192 + ks * 32);
            w0 = q[0]; w1 = q[1];
        }
        b[0] = (short)f2bf(w0.x); b[1] = (short)f2bf(w0.y);
        b[2] = (short)f2bf(w0.z); b[3] = (short)f2bf(w0.w);
        b[4] = (short)f2bf(w1.x); b[5] = (short)f2bf(w1.y);
        b[6] = (short)f2bf(w1.z); b[7] = (short)f2bf(w1.w);
        return b;
    };

    short8 Bf[2][4];
    #pragma unroll
    for (int nf = 0; nf < 4; ++nf) Bf[0][nf] = loadB(0, nf);
    #pragma unroll
    for (int nf = 0; nf < 4; ++nf) Bf[1][nf] = loadB(1, nf);
    __syncthreads();
    #pragma unroll
    for (int ks = 0; ks < 16; ++ks) {
        short8 a[4];
        #pragma unroll
        for (int mf = 0; mf < 4; ++mf) {
            const int addr = (((mf * 16 + l15) << 10) + ks * 64 + lk * 16) ^ a_swz;
            a[mf] = *reinterpret_cast<const short8*>(&Abuf[addr]);
        }
        #pragma unroll
        for (int mf = 0; mf < 4; ++mf)
            #pragma unroll
            for (int nf = 0; nf < 4; ++nf)
                acc[mf][nf] = __builtin_amdgcn_mfma_f32_16x16x32_bf16(a[mf], Bf[ks & 1][nf], acc[mf][nf], 0, 0, 0);
        if (ks < 14) {
            #pragma unroll
            for (int nf = 0; nf < 4; ++nf) Bf[ks & 1][nf] = loadB(ks + 2, nf);
        }
    }
    #pragma unroll
    for (int nf = 0; nf < 4; ++nf) {
        const int col = n_wave + nf * 16 + l15;
        const float bv = (col < 500) ? bias[col] : 0.0f;
        #pragma unroll
        for (int mf = 0; mf < 4; ++mf)
            #pragma unroll
            for (int j = 0; j < 4; ++j)
                acc[mf][nf][j] += bv;
    }
    float* Obuf = reinterpret_cast<float*>(Abuf);
    #pragma unroll
    for (int h = 0; h < 2; ++h) {
        __syncthreads();
        if ((wv >> 2) == h) {
            const int lcol = (wv & 3) << 6;
            #pragma unroll
            for (int mf = 0; mf < 4; ++mf)
                #pragma unroll
                for (int nf = 0; nf < 4; ++nf)
                    #pragma unroll
                    for (int j = 0; j < 4; ++j) {
                        const int r = mf * 16 + lk * 4 + j;
                        Obuf[r * 257 + lcol + nf * 16 + l15] = acc[mf][nf][j];
                    }
        }
        __syncthreads();
        #pragma unroll
        for (int i = 0; i < 8; ++i) {
            const int linear = i * 512 + tid;
            const int r  = linear >> 6;
            const int c4 = linear & 63;
            const int row = m0 + r;
            const int col = (h << 8) + (c4 << 2);
            if (row < M && col < 500) {
                const f32x4 v = *reinterpret_cast<const f32x4*>(&Obuf[r * 257 + (c4 << 2)]);
                __builtin_nontemporal_store(v, reinterpret_cast<f32x4*>(&out[(size_t)row * 500 + col]));
            }
        }
    }
}

extern "C" void kernel_launch(void* const* d_in, const int* in_sizes, int n_in,
                              void* d_out, int out_size, void* d_ws, size_t ws_size,
                              hipStream_t stream) {
    const float* enc  = (const float*)d_in[0];
    const float* dec  = (const float*)d_in[1];
    const float* W    = (const float*)d_in[2];
    const float* bias = (const float*)d_in[3];
    const int* bi = (const int*)d_in[4];
    const int* ti = (const int*)d_in[5];
    const int* ui = (const int*)d_in[6];
    float* out = (float*)d_out;

    const int M = in_sizes[4];
    const int grid = (M + 63) / 64;

    const int enc_n  = in_sizes[0];                    // N*T*D f32 elements
    const int dec_n  = in_sizes[1];                    // N*U*D
    const size_t qw_bytes = (size_t)512 * 512;         // 256 KB i8
    const size_t fac_off  = qw_bytes;                  // f32[512]
    const size_t enc_off  = fac_off + 2048;
    const size_t dec_off  = enc_off + (size_t)enc_n * 2;
    const size_t need_i8  = fac_off + 2048;
    const size_t need_all = dec_off + (size_t)dec_n * 2;

    if (ws_size >= need_all) {
        signed char* qW = (signed char*)d_ws;
        float* fac = (float*)((char*)d_ws + fac_off);
        unsigned short* encB = (unsigned short*)((char*)d_ws + enc_off);
        unsigned short* decB = (unsigned short*)((char*)d_ws + dec_off);
        prep_wq_kernel<<<512, 512, 0, stream>>>(W, qW, fac);
        prep_cast_kernel<<<(enc_n / 4 + 255) / 256, 256, 0, stream>>>(enc, encB, enc_n / 4);
        prep_cast_kernel<<<(dec_n / 4 + 255) / 256, 256, 0, stream>>>(dec, decB, dec_n / 4);
        joiner_i8_kernel<true><<<grid, 512, 0, stream>>>(
            enc, dec, encB, decB, bias, qW, fac, bi, ti, ui, out, M);
    } else if (ws_size >= need_i8) {
        signed char* qW = (signed char*)d_ws;
        float* fac = (float*)((char*)d_ws + fac_off);
        prep_wq_kernel<<<512, 512, 0, stream>>>(W, qW, fac);
        joiner_i8_kernel<false><<<grid, 512, 0, stream>>>(
            enc, dec, nullptr, nullptr, bias, qW, fac, bi, ti, ui, out, M);
    } else {
        joiner_fallback_kernel<<<grid, 512, 0, stream>>>(
            enc, dec, W, bias, bi, ti, ui, out, M);
    }
}